// Round 5
// baseline (336.723 us; speedup 1.0000x reference)
//
#include <hip/hip_runtime.h>
#include <stdint.h>

typedef float f32x4 __attribute__((ext_vector_type(4)));
typedef int   i32x4 __attribute__((ext_vector_type(4)));

// ---------------- Phase A: bucket the scatter indices -----------------------
// 4 k's per thread, nontemporal int4 index loads, 4 independent atomic chains.
// Ticket via atomicAdd on per-row cursor; store pos[k] in the row's slot list
// (capacity 8). Rare overflow (Poisson(2), P[X>8]~2e-4) goes to a side list.
__global__ __launch_bounds__(256) void phaseA_bucket(
    const int* __restrict__ lin, const int* __restrict__ pos, int K,
    unsigned int* __restrict__ cursor, int* __restrict__ slots,
    unsigned int* __restrict__ ovf_cnt, int2* __restrict__ ovf, unsigned int ovf_cap)
{
    int k0 = (blockIdx.x * blockDim.x + threadIdx.x) * 4;
    if (k0 >= K) return;

    if (k0 + 3 < K) {
        i32x4 li = __builtin_nontemporal_load(
            reinterpret_cast<const i32x4*>(lin + k0));
        i32x4 pp = __builtin_nontemporal_load(
            reinterpret_cast<const i32x4*>(pos + k0));
#define PUT(LI, P)                                                         \
        {                                                                  \
            unsigned int t = atomicAdd(&cursor[(LI)], 1u);                 \
            if (t < 8u) {                                                  \
                slots[(long long)(LI) * 8 + t] = (P);                      \
            } else {                                                       \
                unsigned int o = atomicAdd(ovf_cnt, 1u);                   \
                if (o < ovf_cap) ovf[o] = make_int2((LI), (P));            \
            }                                                              \
        }
        PUT(li.x, pp.x) PUT(li.y, pp.y) PUT(li.z, pp.z) PUT(li.w, pp.w)
    } else {
        for (int k = k0; k < K; ++k) {
            int LI = lin[k]; int P = pos[k];
            PUT(LI, P)
        }
    }
#undef PUT
}

// ---------------- Phase B: per-row gather + reduce + plain store ------------
// 16 lanes per row, one float4 per lane (D=64). acc = self + sum(values[pos]).
// Slot list loaded as 2 nontemporal int4; up to 8 independent predicated
// gathers issue back-to-back (MLP=8) before a single wait at the add tree.
// Single-use streams (self/cursor/slots) are nontemporal so L2/L3 keeps
// `values` rows (dup gathers ~37%).
__global__ __launch_bounds__(256) void phaseB_reduce(
    const float* __restrict__ self_t, const float* __restrict__ values,
    const unsigned int* __restrict__ cursor, const int* __restrict__ slots,
    float* __restrict__ out, int Nrows)
{
    long long tid = (long long)blockIdx.x * blockDim.x + threadIdx.x;
    int row = (int)(tid >> 4);
    int sub = (int)(tid & 15);
    if (row >= Nrows) return;

    unsigned int c = __builtin_nontemporal_load(cursor + row);
    if (c > 8u) c = 8u;

    long long base = (long long)row * 64 + (sub << 2);
    f32x4 acc = __builtin_nontemporal_load(
        reinterpret_cast<const f32x4*>(self_t + base));

    if (c) {
        const i32x4* sp = reinterpret_cast<const i32x4*>(slots + (long long)row * 8);
        i32x4 sA = __builtin_nontemporal_load(sp + 0);  // slots 0..3
        i32x4 sB = __builtin_nontemporal_load(sp + 1);  // slots 4..7
        f32x4 v0 = {0,0,0,0}, v1 = {0,0,0,0}, v2 = {0,0,0,0}, v3 = {0,0,0,0};
        f32x4 v4 = {0,0,0,0}, v5 = {0,0,0,0}, v6 = {0,0,0,0}, v7 = {0,0,0,0};
        const long long sh = (long long)(sub << 2);
#define GATHER(j, comp) \
        if (c > (j)) v##j = *reinterpret_cast<const f32x4*>( \
            values + (long long)(comp) * 64 + sh);
        GATHER(0, sA.x) GATHER(1, sA.y) GATHER(2, sA.z) GATHER(3, sA.w)
        GATHER(4, sB.x) GATHER(5, sB.y) GATHER(6, sB.z) GATHER(7, sB.w)
#undef GATHER
        acc += ((v0 + v1) + (v2 + v3)) + ((v4 + v5) + (v6 + v7));
    }
    __builtin_nontemporal_store(acc, reinterpret_cast<f32x4*>(out + base));
}

// ---------------- Phase C: rare overflow entries via atomics ----------------
__global__ __launch_bounds__(256) void phaseC_overflow(
    const unsigned int* __restrict__ ovf_cnt, const int2* __restrict__ ovf,
    unsigned int ovf_cap, const float* __restrict__ values, float* __restrict__ out)
{
    unsigned int n = *ovf_cnt;
    if (n > ovf_cap) n = ovf_cap;
    long long total  = (long long)n * 16;
    long long stride = (long long)gridDim.x * blockDim.x;
    for (long long e = (long long)blockIdx.x * blockDim.x + threadIdx.x;
         e < total; e += stride) {
        int idx = (int)(e >> 4);
        int sub = (int)(e & 15);
        int2 ep = ovf[idx];  // x = row, y = pos
        const float* vp = values + (long long)ep.y * 64 + (sub << 2);
        float* o = out + (long long)ep.x * 64 + (sub << 2);
        atomicAdd(o + 0, vp[0]);
        atomicAdd(o + 1, vp[1]);
        atomicAdd(o + 2, vp[2]);
        atomicAdd(o + 3, vp[3]);
    }
}

// ---------------- Fallback: pure-atomic scatter (ws too small) --------------
__global__ __launch_bounds__(256) void scatter_add_d64(
    const float* __restrict__ values,
    const int*   __restrict__ lin,
    const int*   __restrict__ pos,
    float*       __restrict__ out,
    int K)
{
    long long tid   = (long long)blockIdx.x * blockDim.x + threadIdx.x;
    long long total = (long long)K * 16;
    if (tid >= total) return;
    int k   = (int)(tid >> 4);
    int sub = (int)(tid & 15);
    int li = lin[k];
    int pi = pos[k];
    const float* vp = values + (long long)pi * 64 + (sub << 2);
    float* o = out + (long long)li * 64 + (sub << 2);
    atomicAdd(o + 0, vp[0]);
    atomicAdd(o + 1, vp[1]);
    atomicAdd(o + 2, vp[2]);
    atomicAdd(o + 3, vp[3]);
}

extern "C" void kernel_launch(void* const* d_in, const int* in_sizes, int n_in,
                              void* d_out, int out_size, void* d_ws, size_t ws_size,
                              hipStream_t stream)
{
    const float* self_t = (const float*)d_in[0];   // [N, 64]
    const int*   lin    = (const int*)  d_in[1];   // [K]
    const int*   pos    = (const int*)  d_in[2];   // [K]
    const float* values = (const float*)d_in[3];   // [M, 64]
    float*       out    = (float*)d_out;           // [N, 64]

    const int K = in_sizes[1];
    const int N = in_sizes[0] / 64;

    // Workspace layout: [cursor: 4N][ovf_cnt: 16][ovf: 8K][slots: 32N]
    // cursor+ovf_cnt contiguous -> single memset.
    auto align16 = [](size_t x) { return (x + 15) & ~(size_t)15; };
    size_t cursor_off = 0;
    size_t ovfcnt_off = align16((size_t)N * 4);
    size_t ovf_off    = ovfcnt_off + 16;
    size_t slots_off  = align16(ovf_off + (size_t)K * 8);
    size_t need       = slots_off + (size_t)32 * N;

    if (need > ws_size) {
        // Workspace too small: proven atomic fallback (round-1, 1787 us).
        (void)hipMemcpyAsync(out, self_t, (size_t)out_size * sizeof(float),
                             hipMemcpyDeviceToDevice, stream);
        long long total = (long long)K * 16;
        long long nblk  = (total + 255) / 256;
        scatter_add_d64<<<(int)nblk, 256, 0, stream>>>(values, lin, pos, out, K);
        return;
    }

    char* ws = (char*)d_ws;
    unsigned int* cursor  = (unsigned int*)(ws + cursor_off);
    unsigned int* ovf_cnt = (unsigned int*)(ws + ovfcnt_off);
    int2*         ovf     = (int2*)        (ws + ovf_off);
    int*          slots   = (int*)         (ws + slots_off);
    const unsigned int ovf_cap = (unsigned int)K;

    // Counters must be zero at each call (ws is not re-poisoned between replays).
    (void)hipMemsetAsync(ws, 0, ovfcnt_off + 16, stream);

    // Phase A: bucket (4 k's per thread)
    {
        int nthreads = (K + 3) / 4;
        int nblk = (nthreads + 255) / 256;
        phaseA_bucket<<<nblk, 256, 0, stream>>>(lin, pos, K, cursor, slots,
                                                ovf_cnt, ovf, ovf_cap);
    }
    // Phase B: reduce + store
    {
        long long total = (long long)N * 16;
        long long nblk  = (total + 255) / 256;
        phaseB_reduce<<<(int)nblk, 256, 0, stream>>>(self_t, values, cursor, slots,
                                                     out, N);
    }
    // Phase C: overflow (expected ~hundreds of entries)
    phaseC_overflow<<<512, 256, 0, stream>>>(ovf_cnt, ovf, ovf_cap, values, out);
}

// Round 6
// 314.272 us; speedup vs baseline: 1.0714x; 1.0714x over previous
//
#include <hip/hip_runtime.h>
#include <stdint.h>

typedef float f32x4 __attribute__((ext_vector_type(4)));
typedef int   i32x4 __attribute__((ext_vector_type(4)));

// ---------------- Phase A: bucket the scatter indices -----------------------
// One thread per k (round-4 config: best measured). Ticket via atomicAdd on
// per-row cursor; store pos[k] in the row's slot list (capacity 8). Rare
// overflow (Poisson(2), P[X>8]~2e-4) goes to a side list.
__global__ __launch_bounds__(256) void phaseA_bucket(
    const int* __restrict__ lin, const int* __restrict__ pos, int K,
    unsigned int* __restrict__ cursor, int* __restrict__ slots,
    unsigned int* __restrict__ ovf_cnt, int2* __restrict__ ovf, unsigned int ovf_cap)
{
    int k = blockIdx.x * blockDim.x + threadIdx.x;
    if (k >= K) return;
    int li = lin[k];
    int p  = pos[k];
    unsigned int t = atomicAdd(&cursor[li], 1u);
    if (t < 8u) {
        slots[(long long)li * 8 + t] = p;
    } else {
        unsigned int o = atomicAdd(ovf_cnt, 1u);
        if (o < ovf_cap) ovf[o] = make_int2(li, p);
    }
}

// ---------------- Phase B: per-row gather + reduce + plain store ------------
// 16 lanes per row, one float4 per lane (D=64). acc = self + sum(values[pos]).
// Slot list loaded as 2 int4 (plain loads: slots/cursor are L2-resident from
// phase A — NT hints here regressed in round 5). Up to 8 independent
// predicated gathers issue back-to-back (MLP=8) before one wait at the add
// tree. NT only on the single-use streams: self read, out write.
__global__ __launch_bounds__(256) void phaseB_reduce(
    const float* __restrict__ self_t, const float* __restrict__ values,
    const unsigned int* __restrict__ cursor, const int* __restrict__ slots,
    float* __restrict__ out, int Nrows)
{
    long long tid = (long long)blockIdx.x * blockDim.x + threadIdx.x;
    int row = (int)(tid >> 4);
    int sub = (int)(tid & 15);
    if (row >= Nrows) return;

    unsigned int c = cursor[row];
    if (c > 8u) c = 8u;

    long long base = (long long)row * 64 + (sub << 2);
    f32x4 acc = __builtin_nontemporal_load(
        reinterpret_cast<const f32x4*>(self_t + base));

    if (c) {
        const i32x4* sp = reinterpret_cast<const i32x4*>(slots + (long long)row * 8);
        i32x4 sA = sp[0];          // slots 0..3 (garbage past c never dereferenced)
        i32x4 sB = sp[1];          // slots 4..7
        f32x4 v0 = {0,0,0,0}, v1 = {0,0,0,0}, v2 = {0,0,0,0}, v3 = {0,0,0,0};
        f32x4 v4 = {0,0,0,0}, v5 = {0,0,0,0}, v6 = {0,0,0,0}, v7 = {0,0,0,0};
        const long long sh = (long long)(sub << 2);
#define GATHER(j, comp) \
        if (c > (j)) v##j = *reinterpret_cast<const f32x4*>( \
            values + (long long)(comp) * 64 + sh);
        GATHER(0, sA.x) GATHER(1, sA.y) GATHER(2, sA.z) GATHER(3, sA.w)
        GATHER(4, sB.x) GATHER(5, sB.y) GATHER(6, sB.z) GATHER(7, sB.w)
#undef GATHER
        acc += ((v0 + v1) + (v2 + v3)) + ((v4 + v5) + (v6 + v7));
    }
    __builtin_nontemporal_store(acc, reinterpret_cast<f32x4*>(out + base));
}

// ---------------- Phase C: rare overflow entries via atomics ----------------
__global__ __launch_bounds__(256) void phaseC_overflow(
    const unsigned int* __restrict__ ovf_cnt, const int2* __restrict__ ovf,
    unsigned int ovf_cap, const float* __restrict__ values, float* __restrict__ out)
{
    unsigned int n = *ovf_cnt;
    if (n > ovf_cap) n = ovf_cap;
    long long total  = (long long)n * 16;
    long long stride = (long long)gridDim.x * blockDim.x;
    for (long long e = (long long)blockIdx.x * blockDim.x + threadIdx.x;
         e < total; e += stride) {
        int idx = (int)(e >> 4);
        int sub = (int)(e & 15);
        int2 ep = ovf[idx];  // x = row, y = pos
        const float* vp = values + (long long)ep.y * 64 + (sub << 2);
        float* o = out + (long long)ep.x * 64 + (sub << 2);
        atomicAdd(o + 0, vp[0]);
        atomicAdd(o + 1, vp[1]);
        atomicAdd(o + 2, vp[2]);
        atomicAdd(o + 3, vp[3]);
    }
}

// ---------------- Fallback: pure-atomic scatter (ws too small) --------------
__global__ __launch_bounds__(256) void scatter_add_d64(
    const float* __restrict__ values,
    const int*   __restrict__ lin,
    const int*   __restrict__ pos,
    float*       __restrict__ out,
    int K)
{
    long long tid   = (long long)blockIdx.x * blockDim.x + threadIdx.x;
    long long total = (long long)K * 16;
    if (tid >= total) return;
    int k   = (int)(tid >> 4);
    int sub = (int)(tid & 15);
    int li = lin[k];
    int pi = pos[k];
    const float* vp = values + (long long)pi * 64 + (sub << 2);
    float* o = out + (long long)li * 64 + (sub << 2);
    atomicAdd(o + 0, vp[0]);
    atomicAdd(o + 1, vp[1]);
    atomicAdd(o + 2, vp[2]);
    atomicAdd(o + 3, vp[3]);
}

extern "C" void kernel_launch(void* const* d_in, const int* in_sizes, int n_in,
                              void* d_out, int out_size, void* d_ws, size_t ws_size,
                              hipStream_t stream)
{
    const float* self_t = (const float*)d_in[0];   // [N, 64]
    const int*   lin    = (const int*)  d_in[1];   // [K]
    const int*   pos    = (const int*)  d_in[2];   // [K]
    const float* values = (const float*)d_in[3];   // [M, 64]
    float*       out    = (float*)d_out;           // [N, 64]

    const int K = in_sizes[1];
    const int N = in_sizes[0] / 64;

    // Workspace layout: [cursor: 4N][ovf_cnt: 16][ovf: 8K][slots: 32N]
    // cursor+ovf_cnt contiguous -> single memset.
    auto align16 = [](size_t x) { return (x + 15) & ~(size_t)15; };
    size_t cursor_off = 0;
    size_t ovfcnt_off = align16((size_t)N * 4);
    size_t ovf_off    = ovfcnt_off + 16;
    size_t slots_off  = align16(ovf_off + (size_t)K * 8);
    size_t need       = slots_off + (size_t)32 * N;

    if (need > ws_size) {
        // Workspace too small: proven atomic fallback (round-1, 1787 us).
        (void)hipMemcpyAsync(out, self_t, (size_t)out_size * sizeof(float),
                             hipMemcpyDeviceToDevice, stream);
        long long total = (long long)K * 16;
        long long nblk  = (total + 255) / 256;
        scatter_add_d64<<<(int)nblk, 256, 0, stream>>>(values, lin, pos, out, K);
        return;
    }

    char* ws = (char*)d_ws;
    unsigned int* cursor  = (unsigned int*)(ws + cursor_off);
    unsigned int* ovf_cnt = (unsigned int*)(ws + ovfcnt_off);
    int2*         ovf     = (int2*)        (ws + ovf_off);
    int*          slots   = (int*)         (ws + slots_off);
    const unsigned int ovf_cap = (unsigned int)K;

    // Counters must be zero at each call (ws is not re-poisoned between replays).
    (void)hipMemsetAsync(ws, 0, ovfcnt_off + 16, stream);

    // Phase A: bucket (one k per thread)
    {
        int nblk = (K + 255) / 256;
        phaseA_bucket<<<nblk, 256, 0, stream>>>(lin, pos, K, cursor, slots,
                                                ovf_cnt, ovf, ovf_cap);
    }
    // Phase B: reduce + store
    {
        long long total = (long long)N * 16;
        long long nblk  = (total + 255) / 256;
        phaseB_reduce<<<(int)nblk, 256, 0, stream>>>(self_t, values, cursor, slots,
                                                     out, N);
    }
    // Phase C: overflow (expected ~hundreds of entries)
    phaseC_overflow<<<512, 256, 0, stream>>>(ovf_cnt, ovf, ovf_cap, values, out);
}